// Round 15
// baseline (205.850 us; speedup 1.0000x reference)
//
#include <hip/hip_runtime.h>

#define N_NODES 100000
#define D_IN 32
#define H 64
#define EPS 1e-5f
#define CAP 32
#define OV_CAP 32768
#define LOV_CAP 256
#define NBINS 196   // bins of 512 dst rows (196*512 = 100352 >= 100000)
#define BINSZ 512
#define BINCAP 7168 // mean 6400, sigma ~80 -> +6 sigma; overflow -> ov (exact)
#define QBIN 64     // eighth-bin: dst rows per aggregation block
#define BSTR 16     // binCur stride: 1 counter per 64B line (RMW stream was 1/8ns/line, saturated)

typedef float floatx2 __attribute__((ext_vector_type(2)));

__device__ __forceinline__ unsigned short f2bf(float f) {
    union { float f; unsigned int u; } c; c.f = f;
    unsigned int b = c.u + 0x7FFFu + ((c.u >> 16) & 1u);   // RNE
    return (unsigned short)(b >> 16);
}
__device__ __forceinline__ float bf2f(unsigned short s) {
    union { unsigned int u; float f; } c; c.u = ((unsigned int)s) << 16;
    return c.f;
}

// ================= K_A: LDS radix partition (P1) ∥ MLP =================
// R15: binCur strided to 1 counter/64B line. P1's reservation was 120K RMWs
// on 13 lines = one per 8ns per line ~= the serialization limit; R6's null
// (200/line over 105us = one per 526ns) was far below it, consistent.
__global__ __launch_bounds__(256, 2) void ka_kernel(
    const float* __restrict__ x,
    const float* __restrict__ W1, const float* __restrict__ b1,
    const float* __restrict__ g1, const float* __restrict__ be1,
    const float* __restrict__ W2, const float* __restrict__ b2,
    const float* __restrict__ g2, const float* __restrict__ be2,
    unsigned short* __restrict__ hb, unsigned char* __restrict__ hb8,
    const int* __restrict__ ei, int* __restrict__ part, int* __restrict__ binCur,
    int* __restrict__ ovCnt, int2* __restrict__ ov,
    int E, int SB, int TOT)
{
    const int i = blockIdx.x;
    const int before = (int)((long long)i * SB / TOT);
    const int after  = (int)((long long)(i + 1) * SB / TOT);

    if (after > before) {
        // ---------------- P1: partition 2048 edges into bins ----------------
        __shared__ int hist[NBINS];
        __shared__ int basev[NBINS];

        int t = before * 256 + threadIdx.x;
        int e0 = t * 8;

        int rows[8], cols[8], myofs[8];
        if (e0 + 7 < E) {
            int4 r0 = *(const int4*)(ei + e0);
            int4 r1 = *(const int4*)(ei + e0 + 4);
            int4 c0 = *(const int4*)(ei + E + e0);
            int4 c1 = *(const int4*)(ei + E + e0 + 4);
            rows[0]=r0.x; rows[1]=r0.y; rows[2]=r0.z; rows[3]=r0.w;
            rows[4]=r1.x; rows[5]=r1.y; rows[6]=r1.z; rows[7]=r1.w;
            cols[0]=c0.x; cols[1]=c0.y; cols[2]=c0.z; cols[3]=c0.w;
            cols[4]=c1.x; cols[5]=c1.y; cols[6]=c1.z; cols[7]=c1.w;
        } else {
#pragma unroll
            for (int j = 0; j < 8; ++j) {
                int e = e0 + j;
                if (e < E) { rows[j] = ei[e]; cols[j] = ei[E + e]; }
                else rows[j] = -1;
            }
        }

        if (threadIdx.x < NBINS) hist[threadIdx.x] = 0;
        __syncthreads();

#pragma unroll
        for (int j = 0; j < 8; ++j)
            if (rows[j] >= 0) myofs[j] = atomicAdd(&hist[rows[j] >> 9], 1);
        __syncthreads();

        if (threadIdx.x < NBINS) {
            int h = hist[threadIdx.x];
            if (h > 0) basev[threadIdx.x] = atomicAdd(&binCur[threadIdx.x * BSTR], h);
        }
        __syncthreads();

#pragma unroll
        for (int j = 0; j < 8; ++j) {
            if (rows[j] < 0) continue;
            int bin  = rows[j] >> 9;
            int slot = basev[bin] + myofs[j];
            if (slot < BINCAP) {
                // pack: r_local (9b) | col (17b); col < 100000 < 2^17
                part[bin * BINCAP + slot] = ((rows[j] & (BINSZ - 1)) << 17) | cols[j];
            } else {
                int s = atomicAdd(ovCnt, 1);
                if (s < OV_CAP) ov[s] = make_int2(rows[j], cols[j]);
            }
        }
        return;
    }

    // ---------------- MLP: thread-per-node (unchanged) ----------------
    int gid = (i - before) * 256 + threadIdx.x;
    int node = gid < N_NODES ? gid : N_NODES - 1;

    float xr[D_IN];
    {
        const float4* xp = (const float4*)(x + (long long)node * D_IN);
#pragma unroll
        for (int i2 = 0; i2 < D_IN / 4; ++i2) {
            float4 v = xp[i2];
            xr[4*i2+0] = v.x; xr[4*i2+1] = v.y; xr[4*i2+2] = v.z; xr[4*i2+3] = v.w;
        }
    }

    float h1[H];
#pragma unroll
    for (int jb = 0; jb < H / 4; ++jb) {
        float4 b = *(const float4*)(b1 + jb * 4);
        h1[4*jb+0] = b.x; h1[4*jb+1] = b.y; h1[4*jb+2] = b.z; h1[4*jb+3] = b.w;
    }
#pragma unroll
    for (int k = 0; k < D_IN; ++k) {
        float xk = xr[k];
#pragma unroll
        for (int jb = 0; jb < H / 4; ++jb) {
            float4 w = *(const float4*)(W1 + k * H + jb * 4);
            h1[4*jb+0] += xk * w.x; h1[4*jb+1] += xk * w.y;
            h1[4*jb+2] += xk * w.z; h1[4*jb+3] += xk * w.w;
        }
    }
    {
        float s0=0,s1=0,s2=0,s3=0, q0=0,q1=0,q2=0,q3=0;
#pragma unroll
        for (int j = 0; j < H; j += 4) {
            s0 += h1[j+0]; s1 += h1[j+1]; s2 += h1[j+2]; s3 += h1[j+3];
            q0 += h1[j+0]*h1[j+0]; q1 += h1[j+1]*h1[j+1];
            q2 += h1[j+2]*h1[j+2]; q3 += h1[j+3]*h1[j+3];
        }
        float mu  = (s0+s1+s2+s3) * (1.0f / H);
        float var = (q0+q1+q2+q3) * (1.0f / H) - mu * mu;
        float rs  = rsqrtf(var + EPS);
#pragma unroll
        for (int jb = 0; jb < H / 4; ++jb) {
            float4 g = *(const float4*)(g1 + jb * 4);
            float4 be = *(const float4*)(be1 + jb * 4);
            h1[4*jb+0] = fmaxf((h1[4*jb+0]-mu)*rs*g.x + be.x, 0.0f);
            h1[4*jb+1] = fmaxf((h1[4*jb+1]-mu)*rs*g.y + be.y, 0.0f);
            h1[4*jb+2] = fmaxf((h1[4*jb+2]-mu)*rs*g.z + be.z, 0.0f);
            h1[4*jb+3] = fmaxf((h1[4*jb+3]-mu)*rs*g.w + be.w, 0.0f);
        }
    }

    float h2[H];
#pragma unroll
    for (int jb = 0; jb < H / 4; ++jb) {
        float4 b = *(const float4*)(b2 + jb * 4);
        h2[4*jb+0] = b.x; h2[4*jb+1] = b.y; h2[4*jb+2] = b.z; h2[4*jb+3] = b.w;
    }
#pragma unroll
    for (int k = 0; k < H; ++k) {
        float hk = h1[k];
#pragma unroll
        for (int jb = 0; jb < H / 4; ++jb) {
            float4 w = *(const float4*)(W2 + k * H + jb * 4);
            h2[4*jb+0] += hk * w.x; h2[4*jb+1] += hk * w.y;
            h2[4*jb+2] += hk * w.z; h2[4*jb+3] += hk * w.w;
        }
    }
    {
        float s0=0,s1=0,s2=0,s3=0, q0=0,q1=0,q2=0,q3=0;
#pragma unroll
        for (int j = 0; j < H; j += 4) {
            s0 += h2[j+0]; s1 += h2[j+1]; s2 += h2[j+2]; s3 += h2[j+3];
            q0 += h2[j+0]*h2[j+0]; q1 += h2[j+1]*h2[j+1];
            q2 += h2[j+2]*h2[j+2]; q3 += h2[j+3]*h2[j+3];
        }
        float mu  = (s0+s1+s2+s3) * (1.0f / H);
        float var = (q0+q1+q2+q3) * (1.0f / H) - mu * mu;
        float rs  = rsqrtf(var + EPS);

        unsigned short* hp = hb + (long long)node * H;
        unsigned int w8[H / 4];
#pragma unroll
        for (int jb = 0; jb < H / 4; ++jb) {
            float4 g = *(const float4*)(g2 + jb * 4);
            float4 be = *(const float4*)(be2 + jb * 4);
            float4 v;
            v.x = fmaxf((h2[4*jb+0]-mu)*rs*g.x + be.x, 0.0f);
            v.y = fmaxf((h2[4*jb+1]-mu)*rs*g.y + be.y, 0.0f);
            v.z = fmaxf((h2[4*jb+2]-mu)*rs*g.z + be.z, 0.0f);
            v.w = fmaxf((h2[4*jb+3]-mu)*rs*g.w + be.w, 0.0f);
            ushort4 u;
            u.x = f2bf(v.x); u.y = f2bf(v.y); u.z = f2bf(v.z); u.w = f2bf(v.w);
            *(ushort4*)(hp + 4*jb) = u;
            int lo = __builtin_amdgcn_cvt_pk_fp8_f32(v.x, v.y, 0, false);
            w8[jb] = (unsigned int)__builtin_amdgcn_cvt_pk_fp8_f32(v.z, v.w, lo, true);
        }
        unsigned int* hp8 = (unsigned int*)(hb8 + (long long)node * H);
#pragma unroll
        for (int q = 0; q < H / 16; ++q)
            *(uint4*)(hp8 + q * 4) = make_uint4(w8[4*q+0], w8[4*q+1], w8[4*q+2], w8[4*q+3]);
    }
}

// ================= K_BC: LDS bucket build + R8-form aggregation =================
// R15: QBIN 128 -> 64 (eighth-bins, 1568 blocks ~ 6/CU): R14's 118us carried
// ~42us of overhead over the 76us gather wall, and had only 3 blocks/CU with
// a phase barrier. More, smaller blocks = deeper block-level overlap; the 8x
// redundant part scan is ~45MB streaming (~7us aggregate) — cheap.
__global__ __launch_bounds__(256, 4) void kbc_kernel(
    const int* __restrict__ part, const int* __restrict__ binCur,
    const unsigned short* __restrict__ hb, const unsigned char* __restrict__ hb8,
    float* __restrict__ out,
    const int* __restrict__ ovCnt, const int2* __restrict__ ov)
{
    __shared__ int cnt_l[QBIN];
    __shared__ int bkt_l[QBIN * CAP];   // 8 KB
    __shared__ int lovf[LOV_CAP];       // local bucket-overflow (normally 0)
    __shared__ int nlov;

    const int bin = blockIdx.x >> 3;
    const int egt = blockIdx.x & 7;
    const int rlo = egt * QBIN;
    const int rbase = (bin << 9) + rlo;
    int n = binCur[bin * BSTR]; if (n > BINCAP) n = BINCAP;

    for (int i = threadIdx.x; i < QBIN; i += 256) cnt_l[i] = 0;
    if (threadIdx.x == 0) nlov = 0;
    __syncthreads();

    // ---------- Phase 1: build buckets in LDS (lane-parallel scan) ----------
    const int* p = part + bin * BINCAP;
    for (int idx = threadIdx.x; idx < n; idx += 256) {
        int v = p[idx];
        int rr = (v >> 17) - rlo;
        if (rr >= 0 && rr < QBIN) {
            int pos = atomicAdd(&cnt_l[rr], 1);
            if (pos < CAP) {
                bkt_l[rr * CAP + pos] = v & 0x1FFFF;
            } else {
                int s = atomicAdd(&nlov, 1);
                if (s < LOV_CAP) lovf[s] = (rr << 17) | (v & 0x1FFFF);
            }
        }
    }
    __syncthreads();

    // ---------- Phase 2: R8-form gather + reduce ----------
    const int t   = threadIdx.x & 63;
    const int wid = threadIdx.x >> 6;              // 4 waves
    const int sub = t >> 4;                        // 4 nodes/wave
    const int l   = t & 15;
    const int q   = l & 3;                         // 16B quad within 64B row
    const int g   = l >> 2;                        // edge-group: 8 contiguous slots
    const uint4* h84 = (const uint4*)hb8;          // row = 4 uint4 (64B)

    int nov = *ovCnt; if (nov > OV_CAP) nov = OV_CAP;   // stable: only ka writes
    int nlv = nlov;   if (nlv > LOV_CAP) nlv = LOV_CAP;

    for (int iter = 0; iter < QBIN / 16; ++iter) {
        const int rl   = iter * 16 + wid * 4 + sub;
        const int node = rbase + rl;
        int m = cnt_l[rl]; if (m > CAP) m = CAP;

        int4 ea = *(const int4*)(bkt_l + rl * CAP + g * 8);
        int4 eb = *(const int4*)(bkt_l + rl * CAP + g * 8 + 4);
        int ed[8] = { ea.x, ea.y, ea.z, ea.w, eb.x, eb.y, eb.z, eb.w };
        const int e0 = g * 8;

        float s[16];
#pragma unroll
        for (int j = 0; j < 16; ++j) s[j] = 0.f;

        uint4 vv[8];
#pragma unroll
        for (int k = 0; k < 8; ++k)
            if (e0 + k < m) vv[k] = h84[(ed[k] << 2) + q];

#pragma unroll
        for (int k = 0; k < 8; ++k) {
            if (e0 + k < m) {
                unsigned int w[4] = { vv[k].x, vv[k].y, vv[k].z, vv[k].w };
#pragma unroll
                for (int u = 0; u < 4; ++u) {
                    floatx2 p0 = __builtin_amdgcn_cvt_pk_f32_fp8(w[u], false);
                    floatx2 p1 = __builtin_amdgcn_cvt_pk_f32_fp8(w[u], true);
                    s[4*u+0] += p0.x; s[4*u+1] += p0.y;
                    s[4*u+2] += p1.x; s[4*u+3] += p1.y;
                }
            }
        }

        // butterfly over the 4 edge-groups (all lanes participate)
#pragma unroll
        for (int j = 0; j < 16; ++j) {
            s[j] += __shfl_xor(s[j], 4, 64);
            s[j] += __shfl_xor(s[j], 8, 64);
        }

        const int co = q * 16 + g * 4;
        float a0 = s[g*4+0], a1 = s[g*4+1], a2 = s[g*4+2], a3 = s[g*4+3];

        if (node < N_NODES) {
            // self term (bf16 precision, sequential access)
            uint2 sv = *(const uint2*)(hb + ((long long)node << 6) + co);
            a0 += bf2f((unsigned short)(sv.x & 0xFFFFu));
            a1 += bf2f((unsigned short)(sv.x >> 16));
            a2 += bf2f((unsigned short)(sv.y & 0xFFFFu));
            a3 += bf2f((unsigned short)(sv.y >> 16));

            // ka's bin-overflow drain (normally 0)
            for (int k = 0; k < nov; ++k) {
                int2 rc = ov[k];
                if (rc.x == node) {
                    uint2 vo = *(const uint2*)(hb + ((long long)rc.y << 6) + co);
                    a0 += bf2f((unsigned short)(vo.x & 0xFFFFu));
                    a1 += bf2f((unsigned short)(vo.x >> 16));
                    a2 += bf2f((unsigned short)(vo.y & 0xFFFFu));
                    a3 += bf2f((unsigned short)(vo.y >> 16));
                }
            }
            // local bucket-overflow drain (normally 0)
            for (int k = 0; k < nlv; ++k) {
                int e = lovf[k];
                if ((e >> 17) == rl) {
                    int col = e & 0x1FFFF;
                    uint2 vo = *(const uint2*)(hb + ((long long)col << 6) + co);
                    a0 += bf2f((unsigned short)(vo.x & 0xFFFFu));
                    a1 += bf2f((unsigned short)(vo.x >> 16));
                    a2 += bf2f((unsigned short)(vo.y & 0xFFFFu));
                    a3 += bf2f((unsigned short)(vo.y >> 16));
                }
            }

            *(float4*)(out + ((long long)node << 6) + co) = make_float4(a0, a1, a2, a3);
        }
    }
}

extern "C" void kernel_launch(void* const* d_in, const int* in_sizes, int n_in,
                              void* d_out, int out_size, void* d_ws, size_t ws_size,
                              hipStream_t stream)
{
    const float* x   = (const float*)d_in[0];
    const int*   ei  = (const int*)d_in[1];
    const float* W1  = (const float*)d_in[2];
    const float* b1  = (const float*)d_in[3];
    const float* g1  = (const float*)d_in[4];
    const float* be1 = (const float*)d_in[5];
    const float* W2  = (const float*)d_in[6];
    const float* b2  = (const float*)d_in[7];
    const float* g2  = (const float*)d_in[8];
    const float* be2 = (const float*)d_in[9];

    float* out = (float*)d_out;

    // workspace layout (~25.1 MB)
    char* ws = (char*)d_ws;
    unsigned short* hb     = (unsigned short*)ws;             // 12,800,000 B
    unsigned char*  hb8    = (unsigned char*)(ws + 12800000); //  6,400,000 B
    int*            ovCnt  = (int*)(ws + 19200000);           //         64 B
    int*            binCur = (int*)(ws + 19200064);           //     12,544 B (196 x 64B lines)
    int2*           ov     = (int2*)(ws + 19212608);          //    262,144 B
    int*            part   = (int*)(ws + 19474752);           //  5,619,712 B

    const int E = in_sizes[1] / 2;

    (void)hipMemsetAsync(ws + 19200000, 0, 12608, stream);    // ovCnt + binCur(strided)

    const int SB = ((E + 7) / 8 + 255) / 256;           // 611 partition chunks
    const int MB = (N_NODES + 255) / 256;               // 391 mlp blocks

    // K_A: radix partition ∥ MLP
    ka_kernel<<<SB + MB, 256, 0, stream>>>(
        x, W1, b1, g1, be1, W2, b2, g2, be2, hb, hb8,
        ei, part, binCur, ovCnt, ov, E, SB, SB + MB);

    // K_BC: LDS bucket build + R8-form aggregation (8 eighth-bins per bin)
    kbc_kernel<<<NBINS * 8, 256, 0, stream>>>(part, binCur, hb, hb8, out, ovCnt, ov);
}

// Round 16
// 188.691 us; speedup vs baseline: 1.0909x; 1.0909x over previous
//
#include <hip/hip_runtime.h>

#define N_NODES 100000
#define D_IN 32
#define H 64
#define EPS 1e-5f
#define RSTR 32     // bucket row: 32 entry slots (128B)
#define CAP 32
#define OV_CAP 32768
#define NBINS 196   // bins of 512 dst rows (196*512 = 100352 >= 100000)
#define BINSZ 512
#define BINCAP 7168 // mean 6400, sigma ~80 -> +6 sigma; overflow -> ov (exact)

typedef float floatx2 __attribute__((ext_vector_type(2)));

__device__ __forceinline__ unsigned short f2bf(float f) {
    union { float f; unsigned int u; } c; c.f = f;
    unsigned int b = c.u + 0x7FFFu + ((c.u >> 16) & 1u);   // RNE
    return (unsigned short)(b >> 16);
}
__device__ __forceinline__ float bf2f(unsigned short s) {
    union { unsigned int u; float f; } c; c.u = ((unsigned int)s) << 16;
    return c.f;
}

// ================= K_A: LDS radix partition (P1) ∥ MLP (R11, unchanged) =================
__global__ __launch_bounds__(256, 2) void ka_kernel(
    const float* __restrict__ x,
    const float* __restrict__ W1, const float* __restrict__ b1,
    const float* __restrict__ g1, const float* __restrict__ be1,
    const float* __restrict__ W2, const float* __restrict__ b2,
    const float* __restrict__ g2, const float* __restrict__ be2,
    unsigned short* __restrict__ hb, unsigned char* __restrict__ hb8,
    const int* __restrict__ ei, int* __restrict__ part, int* __restrict__ binCur,
    int* __restrict__ ovCnt, int2* __restrict__ ov,
    int E, int SB, int TOT)
{
    const int i = blockIdx.x;
    const int before = (int)((long long)i * SB / TOT);
    const int after  = (int)((long long)(i + 1) * SB / TOT);

    if (after > before) {
        // ---------------- P1: partition 2048 edges into bins ----------------
        __shared__ int hist[NBINS];
        __shared__ int basev[NBINS];

        int t = before * 256 + threadIdx.x;
        int e0 = t * 8;

        int rows[8], cols[8], myofs[8];
        if (e0 + 7 < E) {
            int4 r0 = *(const int4*)(ei + e0);
            int4 r1 = *(const int4*)(ei + e0 + 4);
            int4 c0 = *(const int4*)(ei + E + e0);
            int4 c1 = *(const int4*)(ei + E + e0 + 4);
            rows[0]=r0.x; rows[1]=r0.y; rows[2]=r0.z; rows[3]=r0.w;
            rows[4]=r1.x; rows[5]=r1.y; rows[6]=r1.z; rows[7]=r1.w;
            cols[0]=c0.x; cols[1]=c0.y; cols[2]=c0.z; cols[3]=c0.w;
            cols[4]=c1.x; cols[5]=c1.y; cols[6]=c1.z; cols[7]=c1.w;
        } else {
#pragma unroll
            for (int j = 0; j < 8; ++j) {
                int e = e0 + j;
                if (e < E) { rows[j] = ei[e]; cols[j] = ei[E + e]; }
                else rows[j] = -1;
            }
        }

        if (threadIdx.x < NBINS) hist[threadIdx.x] = 0;
        __syncthreads();

#pragma unroll
        for (int j = 0; j < 8; ++j)
            if (rows[j] >= 0) myofs[j] = atomicAdd(&hist[rows[j] >> 9], 1);
        __syncthreads();

        if (threadIdx.x < NBINS) {
            int h = hist[threadIdx.x];
            if (h > 0) basev[threadIdx.x] = atomicAdd(&binCur[threadIdx.x], h);
        }
        __syncthreads();

#pragma unroll
        for (int j = 0; j < 8; ++j) {
            if (rows[j] < 0) continue;
            int bin  = rows[j] >> 9;
            int slot = basev[bin] + myofs[j];
            if (slot < BINCAP) {
                // pack: r_local (9b) | col (17b); col < 100000 < 2^17
                part[bin * BINCAP + slot] = ((rows[j] & (BINSZ - 1)) << 17) | cols[j];
            } else {
                int s = atomicAdd(ovCnt, 1);
                if (s < OV_CAP) ov[s] = make_int2(rows[j], cols[j]);
            }
        }
        return;
    }

    // ---------------- MLP: thread-per-node (unchanged) ----------------
    int gid = (i - before) * 256 + threadIdx.x;
    int node = gid < N_NODES ? gid : N_NODES - 1;

    float xr[D_IN];
    {
        const float4* xp = (const float4*)(x + (long long)node * D_IN);
#pragma unroll
        for (int i2 = 0; i2 < D_IN / 4; ++i2) {
            float4 v = xp[i2];
            xr[4*i2+0] = v.x; xr[4*i2+1] = v.y; xr[4*i2+2] = v.z; xr[4*i2+3] = v.w;
        }
    }

    float h1[H];
#pragma unroll
    for (int jb = 0; jb < H / 4; ++jb) {
        float4 b = *(const float4*)(b1 + jb * 4);
        h1[4*jb+0] = b.x; h1[4*jb+1] = b.y; h1[4*jb+2] = b.z; h1[4*jb+3] = b.w;
    }
#pragma unroll
    for (int k = 0; k < D_IN; ++k) {
        float xk = xr[k];
#pragma unroll
        for (int jb = 0; jb < H / 4; ++jb) {
            float4 w = *(const float4*)(W1 + k * H + jb * 4);
            h1[4*jb+0] += xk * w.x; h1[4*jb+1] += xk * w.y;
            h1[4*jb+2] += xk * w.z; h1[4*jb+3] += xk * w.w;
        }
    }
    {
        float s0=0,s1=0,s2=0,s3=0, q0=0,q1=0,q2=0,q3=0;
#pragma unroll
        for (int j = 0; j < H; j += 4) {
            s0 += h1[j+0]; s1 += h1[j+1]; s2 += h1[j+2]; s3 += h1[j+3];
            q0 += h1[j+0]*h1[j+0]; q1 += h1[j+1]*h1[j+1];
            q2 += h1[j+2]*h1[j+2]; q3 += h1[j+3]*h1[j+3];
        }
        float mu  = (s0+s1+s2+s3) * (1.0f / H);
        float var = (q0+q1+q2+q3) * (1.0f / H) - mu * mu;
        float rs  = rsqrtf(var + EPS);
#pragma unroll
        for (int jb = 0; jb < H / 4; ++jb) {
            float4 g = *(const float4*)(g1 + jb * 4);
            float4 be = *(const float4*)(be1 + jb * 4);
            h1[4*jb+0] = fmaxf((h1[4*jb+0]-mu)*rs*g.x + be.x, 0.0f);
            h1[4*jb+1] = fmaxf((h1[4*jb+1]-mu)*rs*g.y + be.y, 0.0f);
            h1[4*jb+2] = fmaxf((h1[4*jb+2]-mu)*rs*g.z + be.z, 0.0f);
            h1[4*jb+3] = fmaxf((h1[4*jb+3]-mu)*rs*g.w + be.w, 0.0f);
        }
    }

    float h2[H];
#pragma unroll
    for (int jb = 0; jb < H / 4; ++jb) {
        float4 b = *(const float4*)(b2 + jb * 4);
        h2[4*jb+0] = b.x; h2[4*jb+1] = b.y; h2[4*jb+2] = b.z; h2[4*jb+3] = b.w;
    }
#pragma unroll
    for (int k = 0; k < H; ++k) {
        float hk = h1[k];
#pragma unroll
        for (int jb = 0; jb < H / 4; ++jb) {
            float4 w = *(const float4*)(W2 + k * H + jb * 4);
            h2[4*jb+0] += hk * w.x; h2[4*jb+1] += hk * w.y;
            h2[4*jb+2] += hk * w.z; h2[4*jb+3] += hk * w.w;
        }
    }
    {
        float s0=0,s1=0,s2=0,s3=0, q0=0,q1=0,q2=0,q3=0;
#pragma unroll
        for (int j = 0; j < H; j += 4) {
            s0 += h2[j+0]; s1 += h2[j+1]; s2 += h2[j+2]; s3 += h2[j+3];
            q0 += h2[j+0]*h2[j+0]; q1 += h2[j+1]*h2[j+1];
            q2 += h2[j+2]*h2[j+2]; q3 += h2[j+3]*h2[j+3];
        }
        float mu  = (s0+s1+s2+s3) * (1.0f / H);
        float var = (q0+q1+q2+q3) * (1.0f / H) - mu * mu;
        float rs  = rsqrtf(var + EPS);

        unsigned short* hp = hb + (long long)node * H;
        unsigned int w8[H / 4];
#pragma unroll
        for (int jb = 0; jb < H / 4; ++jb) {
            float4 g = *(const float4*)(g2 + jb * 4);
            float4 be = *(const float4*)(be2 + jb * 4);
            float4 v;
            v.x = fmaxf((h2[4*jb+0]-mu)*rs*g.x + be.x, 0.0f);
            v.y = fmaxf((h2[4*jb+1]-mu)*rs*g.y + be.y, 0.0f);
            v.z = fmaxf((h2[4*jb+2]-mu)*rs*g.z + be.z, 0.0f);
            v.w = fmaxf((h2[4*jb+3]-mu)*rs*g.w + be.w, 0.0f);
            ushort4 u;
            u.x = f2bf(v.x); u.y = f2bf(v.y); u.z = f2bf(v.z); u.w = f2bf(v.w);
            *(ushort4*)(hp + 4*jb) = u;
            int lo = __builtin_amdgcn_cvt_pk_fp8_f32(v.x, v.y, 0, false);
            w8[jb] = (unsigned int)__builtin_amdgcn_cvt_pk_fp8_f32(v.z, v.w, lo, true);
        }
        unsigned int* hp8 = (unsigned int*)(hb8 + (long long)node * H);
#pragma unroll
        for (int q = 0; q < H / 16; ++q)
            *(uint4*)(hp8 + q * 4) = make_uint4(w8[4*q+0], w8[4*q+1], w8[4*q+2], w8[4*q+3]);
    }
}

// ================= K_B: per-bin bucket build in LDS, sequential write-out (R11) =================
__global__ __launch_bounds__(256, 2) void kb_kernel(
    const int* __restrict__ part, const int* __restrict__ binCur,
    int* __restrict__ cnt, int* __restrict__ bkt,
    int* __restrict__ ovCnt, int2* __restrict__ ov)
{
    __shared__ int cnt_l[BINSZ];
    __shared__ int bkt_l[BINSZ * CAP];   // 64 KB

    const int bin = blockIdx.x;
    int n = binCur[bin];
    if (n > BINCAP) n = BINCAP;
    const int gbase = bin << 9;

    for (int r = threadIdx.x; r < BINSZ; r += 256) cnt_l[r] = 0;
    __syncthreads();

    const int* p = part + bin * BINCAP;
    for (int idx = threadIdx.x; idx < n; idx += 256) {
        int v = p[idx];
        int r = v >> 17;               // v >= 0 always (26-bit pack)
        int c = v & 0x1FFFF;
        int pos = atomicAdd(&cnt_l[r], 1);
        if (pos < CAP) {
            bkt_l[r * CAP + pos] = c;
        } else {
            int s = atomicAdd(ovCnt, 1);
            if (s < OV_CAP) ov[s] = make_int2(gbase + r, c);
        }
    }
    __syncthreads();

    // sequential copy-out: buckets (8 uint4 per row) then counts
    uint4* gb = (uint4*)bkt;
    const uint4* lb = (const uint4*)bkt_l;
    for (int idx = threadIdx.x; idx < BINSZ * 8; idx += 256) {
        int row = idx >> 3;
        if (gbase + row < N_NODES)
            gb[(long long)(gbase + row) * 8 + (idx & 7)] = lb[idx];
    }
    for (int r = threadIdx.x; r < BINSZ; r += 256)
        if (gbase + r < N_NODES) cnt[gbase + r] = cnt_l[r];
}

// ================= K_C: pull aggregation (R8 dwordx4 form) =================
// R16 single delta vs R11: __launch_bounds__(256, 4). Standalone aggr is
// low-pressure (~70 VGPR need; 4 waves/EU budget = 128 -> no spill risk,
// unlike R4/R5 where the fused MLP path spilled and confounded the test).
// 16 waves/CU doubles outstanding random gathers; the gather wall is the
// only latency*concurrency-bound phase left. GUARD: aggr FETCH ~27MB
// (a jump = spill = invalid round).
__global__ __launch_bounds__(256, 4) void aggr_kernel(
    const int* __restrict__ cnt, const int* __restrict__ bkt,
    const unsigned short* __restrict__ hb, const unsigned char* __restrict__ hb8,
    float* __restrict__ out,
    const int* __restrict__ ovCnt, const int2* __restrict__ ov)
{
    const int t    = threadIdx.x & 63;
    const int sub  = t >> 4;                       // 4 nodes/wave
    const int l    = t & 15;
    const int q    = l & 3;                        // 16B quad within 64B row
    const int g    = l >> 2;                       // edge-group: 8 contiguous edges
    const int wave = blockIdx.x * 4 + (threadIdx.x >> 6);
    const int node = wave * 4 + sub;               // grid exact: 6250*16 = 100000

    int m = cnt[node];
    if (m > CAP) m = CAP;
    const int base = node * RSTR;
    const int e0 = g * 8;

    int4 ea = *(const int4*)(bkt + base + g * 8);
    int4 eb = *(const int4*)(bkt + base + g * 8 + 4);
    int ed[8] = { ea.x, ea.y, ea.z, ea.w, eb.x, eb.y, eb.z, eb.w };

    const uint4* h84 = (const uint4*)hb8;          // row = 4 uint4 (64B)

    float s[16];
#pragma unroll
    for (int j = 0; j < 16; ++j) s[j] = 0.f;

    uint4 vv[8];
#pragma unroll
    for (int k = 0; k < 8; ++k)
        if (e0 + k < m) vv[k] = h84[(ed[k] << 2) + q];

#pragma unroll
    for (int k = 0; k < 8; ++k) {
        if (e0 + k < m) {
            unsigned int w[4] = { vv[k].x, vv[k].y, vv[k].z, vv[k].w };
#pragma unroll
            for (int u = 0; u < 4; ++u) {
                floatx2 p0 = __builtin_amdgcn_cvt_pk_f32_fp8(w[u], false);
                floatx2 p1 = __builtin_amdgcn_cvt_pk_f32_fp8(w[u], true);
                s[4*u+0] += p0.x; s[4*u+1] += p0.y;
                s[4*u+2] += p1.x; s[4*u+3] += p1.y;
            }
        }
    }

    // butterfly over the 4 edge-groups (lanes differing in t bits 2-3)
#pragma unroll
    for (int j = 0; j < 16; ++j) {
        s[j] += __shfl_xor(s[j], 4, 64);
        s[j] += __shfl_xor(s[j], 8, 64);
    }

    const int co = q * 16 + g * 4;
    float a0 = s[g*4+0], a1 = s[g*4+1], a2 = s[g*4+2], a3 = s[g*4+3];

    // self term (bf16 precision, sequential access)
    {
        uint2 sv = *(const uint2*)(hb + ((long long)node << 6) + co);
        a0 += bf2f((unsigned short)(sv.x & 0xFFFFu));
        a1 += bf2f((unsigned short)(sv.x >> 16));
        a2 += bf2f((unsigned short)(sv.y & 0xFFFFu));
        a3 += bf2f((unsigned short)(sv.y >> 16));
    }

    // exact overflow drain (normally 0 entries; bin + bucket overflow unified)
    int nov = *ovCnt; if (nov > OV_CAP) nov = OV_CAP;
    for (int i = 0; i < nov; ++i) {
        int2 rc = ov[i];
        if (rc.x == node) {
            uint2 vo = *(const uint2*)(hb + ((long long)rc.y << 6) + co);
            a0 += bf2f((unsigned short)(vo.x & 0xFFFFu));
            a1 += bf2f((unsigned short)(vo.x >> 16));
            a2 += bf2f((unsigned short)(vo.y & 0xFFFFu));
            a3 += bf2f((unsigned short)(vo.y >> 16));
        }
    }

    *(float4*)(out + ((long long)node << 6) + co) = make_float4(a0, a1, a2, a3);
}

extern "C" void kernel_launch(void* const* d_in, const int* in_sizes, int n_in,
                              void* d_out, int out_size, void* d_ws, size_t ws_size,
                              hipStream_t stream)
{
    const float* x   = (const float*)d_in[0];
    const int*   ei  = (const int*)d_in[1];
    const float* W1  = (const float*)d_in[2];
    const float* b1  = (const float*)d_in[3];
    const float* g1  = (const float*)d_in[4];
    const float* be1 = (const float*)d_in[5];
    const float* W2  = (const float*)d_in[6];
    const float* b2  = (const float*)d_in[7];
    const float* g2  = (const float*)d_in[8];
    const float* be2 = (const float*)d_in[9];

    float* out = (float*)d_out;

    // workspace layout (~38.3 MB) — exact R11 layout
    char* ws = (char*)d_ws;
    unsigned short* hb     = (unsigned short*)ws;             // 12,800,000 B
    unsigned char*  hb8    = (unsigned char*)(ws + 12800000); //  6,400,000 B
    int*            cnt    = (int*)(ws + 19200000);           //    400,000 B (fully written by K_B)
    int*            ovCnt  = (int*)(ws + 19600000);           //         64 B
    int2*           ov     = (int2*)(ws + 19600064);          //    262,144 B
    int*            binCur = (int*)(ws + 19862208);           //        784 B (pad to 832)
    int*            bkt    = (int*)(ws + 19863040);           // 12,800,000 B
    int*            part   = (int*)(ws + 32663040);           //  5,619,712 B (196*7168*4)

    const int E = in_sizes[1] / 2;

    // zero ovCnt + ov-span + binCursor in one memset (19,600,000 .. 19,863,040)
    (void)hipMemsetAsync(ws + 19600000, 0, 263040, stream);

    const int SB = ((E + 7) / 8 + 255) / 256;           // 611 partition chunks
    const int MB = (N_NODES + 255) / 256;               // 391 mlp blocks

    // K_A: radix partition ∥ MLP
    ka_kernel<<<SB + MB, 256, 0, stream>>>(
        x, W1, b1, g1, be1, W2, b2, g2, be2, hb, hb8,
        ei, part, binCur, ovCnt, ov, E, SB, SB + MB);

    // K_B: per-bin LDS bucket build, sequential write-out
    kb_kernel<<<NBINS, 256, 0, stream>>>(part, binCur, cnt, bkt, ovCnt, ov);

    // K_C: pull aggregation (occupancy 2 -> 4 blocks/CU, single delta vs R11)
    aggr_kernel<<<N_NODES / 16, 256, 0, stream>>>(cnt, bkt, hb, hb8, out, ovCnt, ov);
}